// Round 11
// baseline (88.383 us; speedup 1.0000x reference)
//
#include <hip/hip_runtime.h>

// DRMM scoring kernel, round 11.
// Shapes: B=32, D=8, QL=16, DL=512, E=300, V=50000, 5 histogram bins.
// Q-SPLIT for occupancy: grid 512 = 2 blocks per doc pair (b,d); block
// (n, h) computes q-rows h*8..h*8+7 for ALL 512 tokens with R4's exact
// per-lane geometry (256 thr, T=2 tokens/lane, depth-5 reload-in-place
// global pipeline). R4 was grid-limited to 1 wave/SIMD (256 blocks = 1
// block/CU); VGPR 204 <= 256 already allowed 2 waves/SIMD -- this supplies
// the second block. Per-(token,q) FMA chain, qn partial-sum pattern, cos,
// binning are all bit-identical to rounds 1-10; histograms are per-q
// independent so ws_hist[n][q] has a single writer (no combine step).
// Norm chain is computed in both halves (+12% VALU, buys exactness).
// Block id = h*256+n so twin blocks share an XCD (%8 round-robin) and
// their identical doc-row gathers hit L2.
// Kernel B replicates the gate/softmax/ffnn epilogue in R4's exact op
// order (same values phase-2 staged) -> output bit-identical.

constexpr int Bn  = 32;
constexpr int Dn  = 8;
constexpr int QLn = 16;
constexpr int QH  = 8;    // q rows per half-block
constexpr int DLn = 512;
constexpr int En  = 300;

__global__ __launch_bounds__(256) void drmm_partial(
    const int*   __restrict__ bq,    // [B,QL]
    const int*   __restrict__ bd,    // [B,D,DL]
    const float* __restrict__ emb,   // [V,E]
    unsigned long long* __restrict__ ws_hist)  // [256][16] packed counts
{
    __shared__ __attribute__((aligned(16))) float q_lds[QH * En]; // 9600 B
    __shared__ float pn_s[QH][17];
    __shared__ float qn_s[QH];
    __shared__ unsigned long long hist_s[QH];

    const int bid  = blockIdx.x;    // 0..511
    const int n    = bid & 255;     // doc pair (b*8 + d)
    const int h    = bid >> 8;      // q half: 0 or 1
    const int qoff = h * QH;
    const int b    = n >> 3;
    const int tid  = threadIdx.x;   // 0..255

    // ---- stage this half's 8 query rows into LDS (float4 granularity) ----
    for (int idx = tid; idx < QH * (En / 4); idx += 256) {    // 600 float4s
        const int  q   = idx / (En / 4);
        const int  c   = idx - q * (En / 4);
        const long tok = bq[b * QLn + qoff + q];
        *reinterpret_cast<float4*>(&q_lds[q * En + c * 4]) =
            *reinterpret_cast<const float4*>(emb + tok * (long)En + c * 4);
    }
    if (tid < QH) hist_s[tid] = 0ull;
    __syncthreads();

    // ---- query norms, same per-row math as rounds 1-10 ----
    if (tid < QH * 16) {
        const int q = tid >> 4, j = tid & 15;
        float pn = 0.f;
        for (int e = j; e < En; e += 16) {
            const float v = q_lds[q * En + e];
            pn = fmaf(v, v, pn);
        }
        pn_s[q][j] = pn;
    }
    __syncthreads();
    if (tid < QH) {
        float sn = 0.f;
        for (int j = 0; j < 16; ++j) sn += pn_s[tid][j];
        qn_s[tid] = sqrtf(sn);
    }
    __syncthreads();

    // ---- per-token cosine sims vs this half's 8 q rows; T=2 ----
    const long tok0 = bd[n * DLn + tid];
    const long tok1 = bd[n * DLn + tid + 256];
    const float* __restrict__ r0 = emb + tok0 * (long)En;
    const float* __restrict__ r1 = emb + tok1 * (long)En;

    float acc0[QH], acc1[QH];
#pragma unroll
    for (int q = 0; q < QH; ++q) { acc0[q] = 0.f; acc1[q] = 0.f; }
    float nr0 = 0.f, nr1 = 0.f;

    // one 4-float chunk for both tokens (chain order identical to R4):
    // norm xyzw for both tokens, then this half's q rows in ascending order.
#define DRMM_CHUNK(d0, d1, EE)                                            \
    do {                                                                  \
        nr0 = fmaf((d0).x, (d0).x, nr0);                                  \
        nr0 = fmaf((d0).y, (d0).y, nr0);                                  \
        nr0 = fmaf((d0).z, (d0).z, nr0);                                  \
        nr0 = fmaf((d0).w, (d0).w, nr0);                                  \
        nr1 = fmaf((d1).x, (d1).x, nr1);                                  \
        nr1 = fmaf((d1).y, (d1).y, nr1);                                  \
        nr1 = fmaf((d1).z, (d1).z, nr1);                                  \
        nr1 = fmaf((d1).w, (d1).w, nr1);                                  \
        _Pragma("unroll")                                                 \
        for (int q = 0; q < QH; ++q) {                                    \
            const float4 qv =                                             \
                *reinterpret_cast<const float4*>(&q_lds[q * En + (EE)]);  \
            float s0 = acc0[q];                                           \
            s0 = fmaf((d0).x, qv.x, s0);                                  \
            s0 = fmaf((d0).y, qv.y, s0);                                  \
            s0 = fmaf((d0).z, qv.z, s0);                                  \
            s0 = fmaf((d0).w, qv.w, s0);                                  \
            acc0[q] = s0;                                                 \
            float s1 = acc1[q];                                           \
            s1 = fmaf((d1).x, qv.x, s1);                                  \
            s1 = fmaf((d1).y, qv.y, s1);                                  \
            s1 = fmaf((d1).z, qv.z, s1);                                  \
            s1 = fmaf((d1).w, qv.w, s1);                                  \
            acc1[q] = s1;                                                 \
        }                                                                 \
    } while (0)

    // compute slot's chunk, then reload the SAME slot from 5 chunks ahead
#define DRMM_STEP_R(SA, SB, EE)                                           \
    do {                                                                  \
        DRMM_CHUNK(SA, SB, (EE));                                         \
        SA = *reinterpret_cast<const float4*>(r0 + (EE) + 20);            \
        SB = *reinterpret_cast<const float4*>(r1 + (EE) + 20);            \
    } while (0)

    // prologue: slots hold chunks 0..4 (10 loads in flight)
    float4 s0a = *reinterpret_cast<const float4*>(r0 + 0);
    float4 s1a = *reinterpret_cast<const float4*>(r1 + 0);
    float4 s0b = *reinterpret_cast<const float4*>(r0 + 4);
    float4 s1b = *reinterpret_cast<const float4*>(r1 + 4);
    float4 s0c = *reinterpret_cast<const float4*>(r0 + 8);
    float4 s1c = *reinterpret_cast<const float4*>(r1 + 8);
    float4 s0d = *reinterpret_cast<const float4*>(r0 + 12);
    float4 s1d = *reinterpret_cast<const float4*>(r1 + 12);
    float4 s0e = *reinterpret_cast<const float4*>(r0 + 16);
    float4 s1e = *reinterpret_cast<const float4*>(r1 + 16);

#pragma unroll 1
    for (int k = 0; k < 14; ++k) {          // chunks 0..69, reload 5..74
        const int e = k * 20;
        DRMM_STEP_R(s0a, s1a, e + 0);
        DRMM_STEP_R(s0b, s1b, e + 4);
        DRMM_STEP_R(s0c, s1c, e + 8);
        DRMM_STEP_R(s0d, s1d, e + 12);
        DRMM_STEP_R(s0e, s1e, e + 16);
    }
    // epilogue: chunks 70..74, no reload
    DRMM_CHUNK(s0a, s1a, 280);
    DRMM_CHUNK(s0b, s1b, 284);
    DRMM_CHUNK(s0c, s1c, 288);
    DRMM_CHUNK(s0d, s1d, 292);
    DRMM_CHUNK(s0e, s1e, 296);
#undef DRMM_STEP_R
#undef DRMM_CHUNK

    const float dn0 = sqrtf(nr0);
    const float dn1 = sqrtf(nr1);

    unsigned long long cnt[QH];
#pragma unroll
    for (int q = 0; q < QH; ++q) {
        unsigned long long v = 0ull;
        {
            const float denom = fmaxf(qn_s[q] * dn0, 1e-8f);
            const float c     = acc0[q] / denom;
            int bin = -1;
            if      (c >= -1.0f && c < -0.5f) bin = 0;
            else if (c >= -0.5f && c <  0.0f) bin = 1;
            else if (c >=  0.0f && c <  0.5f) bin = 2;
            else if (c >=  0.5f && c <  1.0f) bin = 3;
            else if (c ==  1.0f)              bin = 4;
            if (bin >= 0) v += 1ull << (12 * bin);
        }
        {
            const float denom = fmaxf(qn_s[q] * dn1, 1e-8f);
            const float c     = acc1[q] / denom;
            int bin = -1;
            if      (c >= -1.0f && c < -0.5f) bin = 0;
            else if (c >= -0.5f && c <  0.0f) bin = 1;
            else if (c >=  0.0f && c <  0.5f) bin = 2;
            else if (c >=  0.5f && c <  1.0f) bin = 3;
            else if (c ==  1.0f)              bin = 4;
            if (bin >= 0) v += 1ull << (12 * bin);
        }
        cnt[q] = v;
    }

    // wave reduce the packed counters, then one LDS atomic per wave per q
    const int lane = tid & 63;
#pragma unroll
    for (int q = 0; q < QH; ++q) {
        unsigned long long v = cnt[q];
        for (int off = 32; off > 0; off >>= 1) v += __shfl_down(v, off, 64);
        if (lane == 0) atomicAdd(&hist_s[q], v);
    }
    __syncthreads();

    // single writer per (n, q) slot -- no combine needed
    if (tid < QH) ws_hist[n * QLn + qoff + tid] = hist_s[tid];
}

__global__ __launch_bounds__(256) void drmm_final(
    const int*   __restrict__ bq,    // [B,QL]
    const float* __restrict__ emb,   // [V,E]
    const float* __restrict__ w_g,   // [E]
    const float* __restrict__ b_g,   // [1]
    const unsigned long long* __restrict__ ws_hist,  // [256][16]
    const float* __restrict__ w1,    // [5]
    const float* __restrict__ b1,    // [1]
    const float* __restrict__ w2,    // [1]
    const float* __restrict__ b2,    // [1]
    const float* __restrict__ w_o,   // [1]
    const float* __restrict__ b_o,   // [1]
    float*       __restrict__ out)   // [B*D]
{
    __shared__ float pg_s[QLn][17];
    __shared__ float gate_s[QLn];
    __shared__ float tw_s[QLn];
    __shared__ float wsum_s[QLn];

    const int n   = blockIdx.x;   // 0..255
    const int b   = n >> 3;
    const int tid = threadIdx.x;  // 0..255

    // gate partials: identical per-row math to rounds 1-10's phase 2
    // (reads the same emb values the q_lds staging copied).
    {
        const int  q   = tid >> 4, j = tid & 15;
        const long tok = bq[b * QLn + q];
        const float* __restrict__ row = emb + tok * (long)En;
        float pg = 0.f;
        for (int e = j; e < En; e += 16) pg = fmaf(row[e], w_g[e], pg);
        pg_s[q][j] = pg;
    }
    __syncthreads();
    if (tid < QLn) {
        float sg = 0.f;
        for (int j = 0; j < 16; ++j) sg += pg_s[tid][j];
        gate_s[tid] = sg + b_g[0];
    }
    __syncthreads();
    if (tid == 0) {
        float m = gate_s[0];
        for (int q = 1; q < QLn; ++q) m = fmaxf(m, gate_s[q]);
        float ex[QLn];
        float s = 0.f;
        for (int q = 0; q < QLn; ++q) { ex[q] = expf(gate_s[q] - m); s += ex[q]; }
        for (int q = 0; q < QLn; ++q) tw_s[q] = ex[q] / s;
    }
    __syncthreads();
    if (tid < QLn) {
        const unsigned long long hh = ws_hist[n * QLn + tid];
        float f = 0.f;
        f = fmaf((float)((hh >>  0) & 0xFFFull), w1[0], f);
        f = fmaf((float)((hh >> 12) & 0xFFFull), w1[1], f);
        f = fmaf((float)((hh >> 24) & 0xFFFull), w1[2], f);
        f = fmaf((float)((hh >> 36) & 0xFFFull), w1[3], f);
        f = fmaf((float)((hh >> 48) & 0xFFFull), w1[4], f);
        f += b1[0];
        f = f * w2[0] + b2[0];
        wsum_s[tid] = f * tw_s[tid];
    }
    __syncthreads();
    if (tid == 0) {
        float s = 0.f;
        for (int q = 0; q < QLn; ++q) s += wsum_s[q];
        out[n] = s * w_o[0] + b_o[0];
    }
}

extern "C" void kernel_launch(void* const* d_in, const int* in_sizes, int n_in,
                              void* d_out, int out_size, void* d_ws, size_t ws_size,
                              hipStream_t stream) {
    const int*   bq  = (const int*)  d_in[0];  // batch_queries
    // d_in[1] query_len: unused by reference
    const int*   bd  = (const int*)  d_in[2];  // batch_docs
    // d_in[3] doc_len: unused by reference
    const float* emb = (const float*)d_in[4];
    const float* w_g = (const float*)d_in[5];
    const float* b_g = (const float*)d_in[6];
    const float* w1  = (const float*)d_in[7];
    const float* b1  = (const float*)d_in[8];
    const float* w2  = (const float*)d_in[9];
    const float* b2  = (const float*)d_in[10];
    const float* w_o = (const float*)d_in[11];
    const float* b_o = (const float*)d_in[12];

    unsigned long long* ws_hist = (unsigned long long*)d_ws;  // 32 KB

    drmm_partial<<<Bn * Dn * 2, 256, 0, stream>>>(bq, bd, emb, ws_hist);
    drmm_final<<<Bn * Dn, 256, 0, stream>>>(
        bq, emb, w_g, b_g, ws_hist, w1, b1, w2, b2, w_o, b_o, (float*)d_out);
}